// Round 10
// baseline (355.957 us; speedup 1.0000x reference)
//
#include <hip/hip_runtime.h>

// Problem constants
#define B_ 32
#define N_ 4096
#define C_ 768
#define H_ 8
#define DH_ 96
#define TILE 8
#define ROWS 256
#define NT (ROWS / TILE)     // 32 tiles per chunk
#define NCH (N_ / ROWS)      // 16 chunks per batch row
#define TFL (TILE * C_)      // floats per tile buffer (6144)

struct F3 { float x, y, z; };

#define BARL() do { asm volatile("s_waitcnt lgkmcnt(0)" ::: "memory"); \
                    __builtin_amdgcn_s_barrier(); } while (0)

// ---- q[e] = sum_c queries[c] * Wq[e,c] ------------------------------------
__global__ void k_q(const float* __restrict__ queries, const float* __restrict__ Wq,
                    float* __restrict__ q) {
  int e = blockIdx.x;
  int lane = threadIdx.x;
  const float* row = Wq + (size_t)e * C_;
  float acc = 0.f;
#pragma unroll
  for (int p = 0; p < 3; ++p) {
    int c = p * 256 + lane * 4;
    float4 w = *(const float4*)(row + c);
    float4 qa = *(const float4*)(queries + c);
    acc += w.x * qa.x + w.y * qa.y + w.z * qa.z + w.w * qa.w;
  }
#pragma unroll
  for (int off = 32; off; off >>= 1) acc += __shfl_xor(acc, off);
  if (lane == 0) q[e] = acc;
}

// ---- wq_eff[h,c] = sum_d q[h*DH+d] * Wkv[h*DH+d, c] -----------------------
__global__ void k_wqeff(const float* __restrict__ q, const float* __restrict__ Wkv,
                        float* __restrict__ wqe) {
  int i = blockIdx.x * 256 + threadIdx.x;
  int h = i / C_;
  int c = i - h * C_;
  const float* qh = q + h * DH_;
  float acc = 0.f;
  for (int d = 0; d < DH_; ++d)
    acc = fmaf(qh[d], Wkv[(size_t)(h * DH_ + d) * C_ + c], acc);
  wqe[i] = acc;
}

// ---- single-pass fused: dots -> exp(d-20) -> weighted accumulate ----------
// IDENTICAL to R9. Launched TWICE this round (idempotent: pure overwrite of
// part/sout from x,wqe) so that total_R10 - total_R9 = dur(k_fused) — the
// counter row rocprof keeps hiding behind the harness fill dispatches.
__global__ __attribute__((amdgpu_flat_work_group_size(256, 256),
                          amdgpu_waves_per_eu(2, 2))) void k_fused(
    const float* __restrict__ x, const float* __restrict__ wqe,
    float* __restrict__ part, float* __restrict__ sout) {
  extern __shared__ __align__(16) float xdyn[];       // 3 * TFL floats
  __shared__ __align__(16) float wlds[TILE][H_];      // exp weights
  __shared__ float sden[4][4];                        // denominator partials

  const int ch = blockIdx.x, b = blockIdx.y;
  const int tid = threadIdx.x, lane = tid & 63, wid = tid >> 6;
  const int rbase = (wid & 1) * 4;
  const int hbase = (wid >> 1) * 4;
  const int col = lane * 4;
  const float* xc = x + ((size_t)b * N_ + (size_t)ch * ROWS) * C_;

  float4 wqv[4][3];
#pragma unroll
  for (int h = 0; h < 4; ++h)
#pragma unroll
    for (int p = 0; p < 3; ++p)
      wqv[h][p] = *(const float4*)(wqe + (size_t)(hbase + h) * C_ + p * 256 + col);

  float acc[H_][3];
#pragma unroll
  for (int h = 0; h < H_; ++h) { acc[h][0] = 0.f; acc[h][1] = 0.f; acc[h][2] = 0.f; }
  float sreg = 0.f;

#define STAGE(BI, T) do {                                                      \
    const float* gt_ = xc + (size_t)(T) * TFL;                                 \
    float* bn_ = xdyn + (size_t)(BI) * TFL;                                    \
    _Pragma("unroll")                                                          \
    for (int j = 0; j < 6; ++j) {                                              \
      int k = wid * 6 + j;                                                     \
      __builtin_amdgcn_global_load_lds(                                        \
        (const __attribute__((address_space(1))) void*)(gt_ + k * 256 + lane * 4), \
        (__attribute__((address_space(3))) void*)(bn_ + k * 256),              \
        16, 0, 0);                                                             \
    }                                                                          \
  } while (0)

  STAGE(0, 0);
  STAGE(1, 1);

  int bi = 0;
  for (int t = 0; t < NT; ++t) {
    if (t < NT - 1) { asm volatile("s_waitcnt vmcnt(6)" ::: "memory"); }
    else           { asm volatile("s_waitcnt vmcnt(0)" ::: "memory"); }
    BARL();
    if (t + 2 < NT) { int nb = bi + 2; if (nb >= 3) nb -= 3; STAGE(nb, t + 2); }
    const float* xb = xdyn + (size_t)bi * TFL;

    // ---- Phase A: 4 rows x 4 heads ----------------------------------------
#pragma unroll
    for (int rr = 0; rr < 4; ++rr) {
      const int r = rbase + rr;
      const float* xr = xb + r * C_ + col;
      float4 xv0 = *(const float4*)(xr);
      float4 xv1 = *(const float4*)(xr + 256);
      float4 xv2 = *(const float4*)(xr + 512);
      float d[4];
#pragma unroll
      for (int h = 0; h < 4; ++h) {
        float a = xv0.x * wqv[h][0].x;
        a = fmaf(xv0.y, wqv[h][0].y, a);
        a = fmaf(xv0.z, wqv[h][0].z, a);
        a = fmaf(xv0.w, wqv[h][0].w, a);
        a = fmaf(xv1.x, wqv[h][1].x, a);
        a = fmaf(xv1.y, wqv[h][1].y, a);
        a = fmaf(xv1.z, wqv[h][1].z, a);
        a = fmaf(xv1.w, wqv[h][1].w, a);
        a = fmaf(xv2.x, wqv[h][2].x, a);
        a = fmaf(xv2.y, wqv[h][2].y, a);
        a = fmaf(xv2.z, wqv[h][2].z, a);
        a = fmaf(xv2.w, wqv[h][2].w, a);
        d[h] = a;
      }
      const int s1 = lane & 1, s2 = lane & 2;
      float A0 = (s1 ? d[1] : d[0]) + __shfl_xor(s1 ? d[0] : d[1], 1);
      float A1 = (s1 ? d[3] : d[2]) + __shfl_xor(s1 ? d[2] : d[3], 1);
      float Q  = (s2 ? A1 : A0) + __shfl_xor(s2 ? A0 : A1, 2);
      Q += __shfl_xor(Q, 4);
      Q += __shfl_xor(Q, 8);
      Q += __shfl_xor(Q, 16);
      Q += __shfl_xor(Q, 32);
      float w = __expf(Q - 20.f);
      if (lane < 4) { wlds[r][hbase + lane] = w; sreg += w; }
    }
    BARL();

    // ---- Phase C ----------------------------------------------------------
    {
      const int c0 = tid * 3;
#pragma unroll
      for (int r = 0; r < TILE; ++r) {
        float4 wA = *(const float4*)(&wlds[r][0]);
        float4 wB = *(const float4*)(&wlds[r][4]);
        F3 xv = *(const F3*)(xb + r * C_ + c0);
        acc[0][0] = fmaf(wA.x, xv.x, acc[0][0]);
        acc[0][1] = fmaf(wA.x, xv.y, acc[0][1]);
        acc[0][2] = fmaf(wA.x, xv.z, acc[0][2]);
        acc[1][0] = fmaf(wA.y, xv.x, acc[1][0]);
        acc[1][1] = fmaf(wA.y, xv.y, acc[1][1]);
        acc[1][2] = fmaf(wA.y, xv.z, acc[1][2]);
        acc[2][0] = fmaf(wA.z, xv.x, acc[2][0]);
        acc[2][1] = fmaf(wA.z, xv.y, acc[2][1]);
        acc[2][2] = fmaf(wA.z, xv.z, acc[2][2]);
        acc[3][0] = fmaf(wA.w, xv.x, acc[3][0]);
        acc[3][1] = fmaf(wA.w, xv.y, acc[3][1]);
        acc[3][2] = fmaf(wA.w, xv.z, acc[3][2]);
        acc[4][0] = fmaf(wB.x, xv.x, acc[4][0]);
        acc[4][1] = fmaf(wB.x, xv.y, acc[4][1]);
        acc[4][2] = fmaf(wB.x, xv.z, acc[4][2]);
        acc[5][0] = fmaf(wB.y, xv.x, acc[5][0]);
        acc[5][1] = fmaf(wB.y, xv.y, acc[5][1]);
        acc[5][2] = fmaf(wB.y, xv.z, acc[5][2]);
        acc[6][0] = fmaf(wB.z, xv.x, acc[6][0]);
        acc[6][1] = fmaf(wB.z, xv.y, acc[6][1]);
        acc[6][2] = fmaf(wB.z, xv.z, acc[6][2]);
        acc[7][0] = fmaf(wB.w, xv.x, acc[7][0]);
        acc[7][1] = fmaf(wB.w, xv.y, acc[7][1]);
        acc[7][2] = fmaf(wB.w, xv.z, acc[7][2]);
      }
    }
    ++bi; if (bi >= 3) bi -= 3;
  }

  // ---- epilogue -------------------------------------------------------------
  {
    const int c0 = tid * 3;
    float* pp = part + ((size_t)(b * NCH + ch) * H_) * C_ + c0;
#pragma unroll
    for (int h = 0; h < H_; ++h) {
      F3 o = { acc[h][0], acc[h][1], acc[h][2] };
      *(F3*)(pp + (size_t)h * C_) = o;
    }
    if (lane < 4) sden[wid][lane] = sreg;
    BARL();
    if (tid < H_) {
      int hh = tid >> 2;
      float den = sden[2 * hh][tid & 3] + sden[2 * hh + 1][tid & 3];
      sout[(size_t)(b * NCH + ch) * H_ + tid] = den;
    }
  }
#undef STAGE
}

// ---- combine chunk partials -> xbar = sum part / sum s --------------------
__global__ __launch_bounds__(256) void k_comb(const float* __restrict__ part,
    const float* __restrict__ spart, float* __restrict__ xbar) {
  int i = blockIdx.x * 256 + threadIdx.x;   // < B*H*C
  int bh = i / C_;
  int c  = i - bh * C_;
  int b = bh / H_, h = bh - b * H_;
  const float* sp = spart + (size_t)b * NCH * H_ + h;
  const float* pp = part + ((size_t)b * NCH * H_ + h) * C_ + c;
  float denom = 0.f, acc = 0.f;
#pragma unroll 4
  for (int ch = 0; ch < NCH; ++ch) {
    denom += sp[(size_t)ch * H_];
    acc   += pp[(size_t)ch * H_ * C_];
  }
  xbar[i] = acc / denom;
}

// ---- out1[b,e] = sum_c xbar[b, e/DH, c] * Wkv[C+e, c] ---------------------
__global__ __launch_bounds__(256) void k_out1(const float* __restrict__ xbar,
    const float* __restrict__ Wkv, float* __restrict__ out1) {
  int wv = threadIdx.x >> 6, lane = threadIdx.x & 63;
  int e0 = blockIdx.x * 64 + wv * 16;
  int b0 = blockIdx.y * 8;
  for (int it = 0; it < 16; ++it) {
    int e = e0 + it;
    int h = e / DH_;
    const float* wr = Wkv + (size_t)(C_ + e) * C_ + lane * 4;
    float4 w0 = *(const float4*)(wr);
    float4 w1 = *(const float4*)(wr + 256);
    float4 w2 = *(const float4*)(wr + 512);
    for (int bb = 0; bb < 8; ++bb) {
      int b = b0 + bb;
      const float* xr = xbar + ((size_t)b * H_ + h) * C_ + lane * 4;
      float4 x0 = *(const float4*)(xr);
      float4 x1 = *(const float4*)(xr + 256);
      float4 x2 = *(const float4*)(xr + 512);
      float a = w0.x * x0.x;
      a = fmaf(w0.y, x0.y, a); a = fmaf(w0.z, x0.z, a); a = fmaf(w0.w, x0.w, a);
      a = fmaf(w1.x, x1.x, a); a = fmaf(w1.y, x1.y, a);
      a = fmaf(w1.z, x1.z, a); a = fmaf(w1.w, x1.w, a);
      a = fmaf(w2.x, x2.x, a); a = fmaf(w2.y, x2.y, a);
      a = fmaf(w2.z, x2.z, a); a = fmaf(w2.w, x2.w, a);
#pragma unroll
      for (int off = 32; off; off >>= 1) a += __shfl_xor(a, off);
      if (lane == 0) out1[(size_t)b * C_ + e] = a;
    }
  }
}

// ---- y[b,e] = sum_c out1[b,c] * Wproj[e,c] + bproj[e] ---------------------
__global__ __launch_bounds__(256) void k_proj(const float* __restrict__ out1,
    const float* __restrict__ Wproj, const float* __restrict__ bproj,
    float* __restrict__ y) {
  int wv = threadIdx.x >> 6, lane = threadIdx.x & 63;
  int e0 = blockIdx.x * 64 + wv * 16;
  int b0 = blockIdx.y * 8;
  for (int it = 0; it < 16; ++it) {
    int e = e0 + it;
    const float* wr = Wproj + (size_t)e * C_ + lane * 4;
    float4 w0 = *(const float4*)(wr);
    float4 w1 = *(const float4*)(wr + 256);
    float4 w2 = *(const float4*)(wr + 512);
    for (int bb = 0; bb < 8; ++bb) {
      int b = b0 + bb;
      const float* xr = out1 + (size_t)b * C_ + lane * 4;
      float4 x0 = *(const float4*)(xr);
      float4 x1 = *(const float4*)(xr + 256);
      float4 x2 = *(const float4*)(xr + 512);
      float a = w0.x * x0.x;
      a = fmaf(w0.y, x0.y, a); a = fmaf(w0.z, x0.z, a); a = fmaf(w0.w, x0.w, a);
      a = fmaf(w1.x, x1.x, a); a = fmaf(w1.y, x1.y, a);
      a = fmaf(w1.z, x1.z, a); a = fmaf(w1.w, x1.w, a);
      a = fmaf(w2.x, x2.x, a); a = fmaf(w2.y, x2.y, a);
      a = fmaf(w2.z, x2.z, a); a = fmaf(w2.w, x2.w, a);
#pragma unroll
      for (int off = 32; off; off >>= 1) a += __shfl_xor(a, off);
      if (lane == 0) y[(size_t)b * C_ + e] = a + bproj[e];
    }
  }
}

extern "C" void kernel_launch(void* const* d_in, const int* in_sizes, int n_in,
                              void* d_out, int out_size, void* d_ws, size_t ws_size,
                              hipStream_t stream) {
  const float* x       = (const float*)d_in[0];
  const float* queries = (const float*)d_in[1];
  const float* Wq      = (const float*)d_in[2];
  const float* Wkv     = (const float*)d_in[3];
  const float* Wproj   = (const float*)d_in[4];
  const float* bproj   = (const float*)d_in[5];
  float* y  = (float*)d_out;
  float* ws = (float*)d_ws;

  float* q     = ws;                                   // 768
  float* wqe   = ws + 1024;                            // 6144
  float* spart = ws + 8192;                            // B*NCH*H = 4096
  float* part  = ws + 16384;                           // B*NCH*H*C = 3145728
  float* xbar  = part + (size_t)B_ * NCH * H_ * C_;    // 196608
  float* out1  = xbar + (size_t)B_ * H_ * C_;          // 24576

  hipLaunchKernelGGL(k_q,     dim3(C_),            dim3(64),  0, stream, queries, Wq, q);
  hipLaunchKernelGGL(k_wqeff, dim3(H_ * C_ / 256), dim3(256), 0, stream, q, Wkv, wqe);
  // MEASUREMENT: k_fused launched twice (idempotent). total_R10 - total_R9
  // isolates dur(k_fused), which rocprof top-5 has never shown.
  hipLaunchKernelGGL(k_fused, dim3(NCH, B_),       dim3(256),
                     3 * TFL * sizeof(float), stream, x, wqe, part, spart);
  hipLaunchKernelGGL(k_fused, dim3(NCH, B_),       dim3(256),
                     3 * TFL * sizeof(float), stream, x, wqe, part, spart);
  hipLaunchKernelGGL(k_comb,  dim3(B_ * H_ * C_ / 256), dim3(256), 0, stream, part, spart, xbar);
  hipLaunchKernelGGL(k_out1,  dim3(12, 4),         dim3(256), 0, stream, xbar, Wkv, out1);
  hipLaunchKernelGGL(k_proj,  dim3(12, 4),         dim3(256), 0, stream, out1, Wproj, bproj, y);
}

// Round 11
// 278.392 us; speedup vs baseline: 1.2786x; 1.2786x over previous
//
#include <hip/hip_runtime.h>
#include <hip/hip_cooperative_groups.h>

namespace cg = cooperative_groups;

// Problem constants
#define B_ 32
#define N_ 4096
#define C_ 768
#define H_ 8
#define DH_ 96
#define TILE 8
#define ROWS 256
#define NT (ROWS / TILE)     // 32 tiles per chunk
#define NCH (N_ / ROWS)      // 16 chunks per batch row
#define TFL (TILE * C_)      // floats per tile buffer (6144)

struct F3 { float x, y, z; };

#define BARL() do { asm volatile("s_waitcnt lgkmcnt(0)" ::: "memory"); \
                    __builtin_amdgcn_s_barrier(); } while (0)

// ---- prep: q (LDS-only) then wqe_eff -------------------------------------
// grid 24 blocks x 256. Block bid: h = bid/3, c-range = (bid%3)*256 .. +255.
// Phase 1: qh[d] = dot(queries, Wq[h*96+d])  (wave-per-dot, 24 per wave)
// Phase 2: wqe[h,c] = sum_d qh[d] * Wkv[h*96+d, c]
__global__ __launch_bounds__(256) void k_prep(const float* __restrict__ queries,
    const float* __restrict__ Wq, const float* __restrict__ Wkv,
    float* __restrict__ wqe) {
  __shared__ float qh[DH_];
  const int bid = blockIdx.x;
  const int h = bid / 3, coff = (bid % 3) * 256;
  const int tid = threadIdx.x, lane = tid & 63, wv = tid >> 6;

  float4 q0 = *(const float4*)(queries + lane * 4);
  float4 q1 = *(const float4*)(queries + 256 + lane * 4);
  float4 q2 = *(const float4*)(queries + 512 + lane * 4);
#pragma unroll 4
  for (int j = 0; j < 24; ++j) {
    int d = wv * 24 + j;
    const float* wr = Wq + (size_t)(h * DH_ + d) * C_ + lane * 4;
    float4 w0 = *(const float4*)(wr);
    float4 w1 = *(const float4*)(wr + 256);
    float4 w2 = *(const float4*)(wr + 512);
    float a = w0.x * q0.x;
    a = fmaf(w0.y, q0.y, a); a = fmaf(w0.z, q0.z, a); a = fmaf(w0.w, q0.w, a);
    a = fmaf(w1.x, q1.x, a); a = fmaf(w1.y, q1.y, a);
    a = fmaf(w1.z, q1.z, a); a = fmaf(w1.w, q1.w, a);
    a = fmaf(w2.x, q2.x, a); a = fmaf(w2.y, q2.y, a);
    a = fmaf(w2.z, q2.z, a); a = fmaf(w2.w, q2.w, a);
#pragma unroll
    for (int off = 32; off; off >>= 1) a += __shfl_xor(a, off);
    if (lane == 0) qh[d] = a;
  }
  __syncthreads();

  const int c = coff + tid;
  const float* base = Wkv + (size_t)h * DH_ * C_ + c;
  float a = 0.f;
#pragma unroll 8
  for (int d = 0; d < DH_; ++d)
    a = fmaf(qh[d], base[(size_t)d * C_], a);
  wqe[(size_t)h * C_ + c] = a;
}

// ---- single-pass fused: dots -> exp(d-20) -> weighted accumulate ----------
// IDENTICAL to R9/R10 (measured 111 us). Optimize next round.
__global__ __attribute__((amdgpu_flat_work_group_size(256, 256),
                          amdgpu_waves_per_eu(2, 2))) void k_fused(
    const float* __restrict__ x, const float* __restrict__ wqe,
    float* __restrict__ part, float* __restrict__ sout) {
  extern __shared__ __align__(16) float xdyn[];       // 3 * TFL floats
  __shared__ __align__(16) float wlds[TILE][H_];
  __shared__ float sden[4][4];

  const int ch = blockIdx.x, b = blockIdx.y;
  const int tid = threadIdx.x, lane = tid & 63, wid = tid >> 6;
  const int rbase = (wid & 1) * 4;
  const int hbase = (wid >> 1) * 4;
  const int col = lane * 4;
  const float* xc = x + ((size_t)b * N_ + (size_t)ch * ROWS) * C_;

  float4 wqv[4][3];
#pragma unroll
  for (int h = 0; h < 4; ++h)
#pragma unroll
    for (int p = 0; p < 3; ++p)
      wqv[h][p] = *(const float4*)(wqe + (size_t)(hbase + h) * C_ + p * 256 + col);

  float acc[H_][3];
#pragma unroll
  for (int h = 0; h < H_; ++h) { acc[h][0] = 0.f; acc[h][1] = 0.f; acc[h][2] = 0.f; }
  float sreg = 0.f;

#define STAGE(BI, T) do {                                                      \
    const float* gt_ = xc + (size_t)(T) * TFL;                                 \
    float* bn_ = xdyn + (size_t)(BI) * TFL;                                    \
    _Pragma("unroll")                                                          \
    for (int j = 0; j < 6; ++j) {                                              \
      int k = wid * 6 + j;                                                     \
      __builtin_amdgcn_global_load_lds(                                        \
        (const __attribute__((address_space(1))) void*)(gt_ + k * 256 + lane * 4), \
        (__attribute__((address_space(3))) void*)(bn_ + k * 256),              \
        16, 0, 0);                                                             \
    }                                                                          \
  } while (0)

  STAGE(0, 0);
  STAGE(1, 1);

  int bi = 0;
  for (int t = 0; t < NT; ++t) {
    if (t < NT - 1) { asm volatile("s_waitcnt vmcnt(6)" ::: "memory"); }
    else           { asm volatile("s_waitcnt vmcnt(0)" ::: "memory"); }
    BARL();
    if (t + 2 < NT) { int nb = bi + 2; if (nb >= 3) nb -= 3; STAGE(nb, t + 2); }
    const float* xb = xdyn + (size_t)bi * TFL;

#pragma unroll
    for (int rr = 0; rr < 4; ++rr) {
      const int r = rbase + rr;
      const float* xr = xb + r * C_ + col;
      float4 xv0 = *(const float4*)(xr);
      float4 xv1 = *(const float4*)(xr + 256);
      float4 xv2 = *(const float4*)(xr + 512);
      float d[4];
#pragma unroll
      for (int h = 0; h < 4; ++h) {
        float a = xv0.x * wqv[h][0].x;
        a = fmaf(xv0.y, wqv[h][0].y, a);
        a = fmaf(xv0.z, wqv[h][0].z, a);
        a = fmaf(xv0.w, wqv[h][0].w, a);
        a = fmaf(xv1.x, wqv[h][1].x, a);
        a = fmaf(xv1.y, wqv[h][1].y, a);
        a = fmaf(xv1.z, wqv[h][1].z, a);
        a = fmaf(xv1.w, wqv[h][1].w, a);
        a = fmaf(xv2.x, wqv[h][2].x, a);
        a = fmaf(xv2.y, wqv[h][2].y, a);
        a = fmaf(xv2.z, wqv[h][2].z, a);
        a = fmaf(xv2.w, wqv[h][2].w, a);
        d[h] = a;
      }
      const int s1 = lane & 1, s2 = lane & 2;
      float A0 = (s1 ? d[1] : d[0]) + __shfl_xor(s1 ? d[0] : d[1], 1);
      float A1 = (s1 ? d[3] : d[2]) + __shfl_xor(s1 ? d[2] : d[3], 1);
      float Q  = (s2 ? A1 : A0) + __shfl_xor(s2 ? A0 : A1, 2);
      Q += __shfl_xor(Q, 4);
      Q += __shfl_xor(Q, 8);
      Q += __shfl_xor(Q, 16);
      Q += __shfl_xor(Q, 32);
      float w = __expf(Q - 20.f);
      if (lane < 4) { wlds[r][hbase + lane] = w; sreg += w; }
    }
    BARL();

    {
      const int c0 = tid * 3;
#pragma unroll
      for (int r = 0; r < TILE; ++r) {
        float4 wA = *(const float4*)(&wlds[r][0]);
        float4 wB = *(const float4*)(&wlds[r][4]);
        F3 xv = *(const F3*)(xb + r * C_ + c0);
        acc[0][0] = fmaf(wA.x, xv.x, acc[0][0]);
        acc[0][1] = fmaf(wA.x, xv.y, acc[0][1]);
        acc[0][2] = fmaf(wA.x, xv.z, acc[0][2]);
        acc[1][0] = fmaf(wA.y, xv.x, acc[1][0]);
        acc[1][1] = fmaf(wA.y, xv.y, acc[1][1]);
        acc[1][2] = fmaf(wA.y, xv.z, acc[1][2]);
        acc[2][0] = fmaf(wA.z, xv.x, acc[2][0]);
        acc[2][1] = fmaf(wA.z, xv.y, acc[2][1]);
        acc[2][2] = fmaf(wA.z, xv.z, acc[2][2]);
        acc[3][0] = fmaf(wA.w, xv.x, acc[3][0]);
        acc[3][1] = fmaf(wA.w, xv.y, acc[3][1]);
        acc[3][2] = fmaf(wA.w, xv.z, acc[3][2]);
        acc[4][0] = fmaf(wB.x, xv.x, acc[4][0]);
        acc[4][1] = fmaf(wB.x, xv.y, acc[4][1]);
        acc[4][2] = fmaf(wB.x, xv.z, acc[4][2]);
        acc[5][0] = fmaf(wB.y, xv.x, acc[5][0]);
        acc[5][1] = fmaf(wB.y, xv.y, acc[5][1]);
        acc[5][2] = fmaf(wB.y, xv.z, acc[5][2]);
        acc[6][0] = fmaf(wB.z, xv.x, acc[6][0]);
        acc[6][1] = fmaf(wB.z, xv.y, acc[6][1]);
        acc[6][2] = fmaf(wB.z, xv.z, acc[6][2]);
        acc[7][0] = fmaf(wB.w, xv.x, acc[7][0]);
        acc[7][1] = fmaf(wB.w, xv.y, acc[7][1]);
        acc[7][2] = fmaf(wB.w, xv.z, acc[7][2]);
      }
    }
    ++bi; if (bi >= 3) bi -= 3;
  }

  {
    const int c0 = tid * 3;
    float* pp = part + ((size_t)(b * NCH + ch) * H_) * C_ + c0;
#pragma unroll
    for (int h = 0; h < H_; ++h) {
      F3 o = { acc[h][0], acc[h][1], acc[h][2] };
      *(F3*)(pp + (size_t)h * C_) = o;
    }
    if (lane < 4) sden[wid][lane] = sreg;
    BARL();
    if (tid < H_) {
      int hh = tid >> 2;
      float den = sden[2 * hh][tid & 3] + sden[2 * hh + 1][tid & 3];
      sout[(size_t)(b * NCH + ch) * H_ + tid] = den;
    }
  }
#undef STAGE
}

// ---- cooperative tail: comb -> out1 -> proj with grid syncs ---------------
// grid 256 x 256 (1 small block per CU, co-resident).
// Phase 1: xbar = (sum_ch part) / (sum_ch spart)   [elementwise, 3/thread]
// Phase 2: out1[b,e] = dot(xbar[b,e/96], WkvB[e])  [block = (b, e-slice of 96)]
// Phase 3: y[b,e] = dot(out1[b], Wproj[e]) + bproj[e]
__global__ __launch_bounds__(256) void k_tail(
    const float* __restrict__ part, const float* __restrict__ spart,
    const float* __restrict__ Wkv, const float* __restrict__ Wproj,
    const float* __restrict__ bproj, float* __restrict__ xbar,
    float* __restrict__ out1, float* __restrict__ y) {
  cg::grid_group grid = cg::this_grid();
  const int bid = blockIdx.x, tid = threadIdx.x;
  const int lane = tid & 63, wv = tid >> 6;

  // ---- Phase 1: comb ------------------------------------------------------
  {
    const int base = (bid * 256 + tid) * 3;         // < B*H*C, never crosses h
    const int b = base / (H_ * C_);
    const int rem = base - b * (H_ * C_);
    const int h = rem / C_;
    const int c0 = rem - h * C_;
    const float* sp = spart + (size_t)b * NCH * H_ + h;
    const float* pp = part + ((size_t)b * NCH * H_ + h) * C_ + c0;
    float den = 0.f, a0 = 0.f, a1 = 0.f, a2 = 0.f;
#pragma unroll 4
    for (int ch = 0; ch < NCH; ++ch) {
      den += sp[(size_t)ch * H_];
      const float* p = pp + (size_t)ch * H_ * C_;
      a0 += p[0]; a1 += p[1]; a2 += p[2];
    }
    float inv = 1.f / den;
    xbar[base] = a0 * inv; xbar[base + 1] = a1 * inv; xbar[base + 2] = a2 * inv;
  }
  __threadfence();
  grid.sync();

  // ---- Phase 2: out1 ------------------------------------------------------
  {
    const int b = bid >> 3, esl = bid & 7;          // e-range esl*96..+95, h = esl
    const float* xr = xbar + (size_t)(b * H_ + esl) * C_ + lane * 4;
    float4 x0 = *(const float4*)(xr);
    float4 x1 = *(const float4*)(xr + 256);
    float4 x2 = *(const float4*)(xr + 512);
#pragma unroll 4
    for (int j = 0; j < 24; ++j) {
      int e = esl * 96 + wv * 24 + j;
      const float* wr = Wkv + (size_t)(C_ + e) * C_ + lane * 4;
      float4 w0 = *(const float4*)(wr);
      float4 w1 = *(const float4*)(wr + 256);
      float4 w2 = *(const float4*)(wr + 512);
      float a = w0.x * x0.x;
      a = fmaf(w0.y, x0.y, a); a = fmaf(w0.z, x0.z, a); a = fmaf(w0.w, x0.w, a);
      a = fmaf(w1.x, x1.x, a); a = fmaf(w1.y, x1.y, a);
      a = fmaf(w1.z, x1.z, a); a = fmaf(w1.w, x1.w, a);
      a = fmaf(w2.x, x2.x, a); a = fmaf(w2.y, x2.y, a);
      a = fmaf(w2.z, x2.z, a); a = fmaf(w2.w, x2.w, a);
#pragma unroll
      for (int off = 32; off; off >>= 1) a += __shfl_xor(a, off);
      if (lane == 0) out1[(size_t)b * C_ + e] = a;
    }
  }
  __threadfence();
  grid.sync();

  // ---- Phase 3: proj ------------------------------------------------------
  {
    const int b = bid >> 3, esl = bid & 7;
    const float* xr = out1 + (size_t)b * C_ + lane * 4;
    float4 x0 = *(const float4*)(xr);
    float4 x1 = *(const float4*)(xr + 256);
    float4 x2 = *(const float4*)(xr + 512);
#pragma unroll 4
    for (int j = 0; j < 24; ++j) {
      int e = esl * 96 + wv * 24 + j;
      const float* wr = Wproj + (size_t)e * C_ + lane * 4;
      float4 w0 = *(const float4*)(wr);
      float4 w1 = *(const float4*)(wr + 256);
      float4 w2 = *(const float4*)(wr + 512);
      float a = w0.x * x0.x;
      a = fmaf(w0.y, x0.y, a); a = fmaf(w0.z, x0.z, a); a = fmaf(w0.w, x0.w, a);
      a = fmaf(w1.x, x1.x, a); a = fmaf(w1.y, x1.y, a);
      a = fmaf(w1.z, x1.z, a); a = fmaf(w1.w, x1.w, a);
      a = fmaf(w2.x, x2.x, a); a = fmaf(w2.y, x2.y, a);
      a = fmaf(w2.z, x2.z, a); a = fmaf(w2.w, x2.w, a);
#pragma unroll
      for (int off = 32; off; off >>= 1) a += __shfl_xor(a, off);
      if (lane == 0) y[(size_t)b * C_ + e] = a + bproj[e];
    }
  }
}

extern "C" void kernel_launch(void* const* d_in, const int* in_sizes, int n_in,
                              void* d_out, int out_size, void* d_ws, size_t ws_size,
                              hipStream_t stream) {
  const float* x       = (const float*)d_in[0];
  const float* queries = (const float*)d_in[1];
  const float* Wq      = (const float*)d_in[2];
  const float* Wkv     = (const float*)d_in[3];
  const float* Wproj   = (const float*)d_in[4];
  const float* bproj   = (const float*)d_in[5];
  float* y  = (float*)d_out;
  float* ws = (float*)d_ws;

  float* wqe   = ws + 1024;                            // 6144
  float* spart = ws + 8192;                            // B*NCH*H = 4096
  float* part  = ws + 16384;                           // B*NCH*H*C = 3145728
  float* xbar  = part + (size_t)B_ * NCH * H_ * C_;    // 196608
  float* out1  = xbar + (size_t)B_ * H_ * C_;          // 24576

  hipLaunchKernelGGL(k_prep, dim3(24), dim3(256), 0, stream, queries, Wq, Wkv, wqe);
  hipLaunchKernelGGL(k_fused, dim3(NCH, B_), dim3(256),
                     3 * TFL * sizeof(float), stream, x, wqe, part, spart);

  void* targs[] = { (void*)&part, (void*)&spart, (void*)&Wkv, (void*)&Wproj,
                    (void*)&bproj, (void*)&xbar, (void*)&out1, (void*)&y };
  hipLaunchCooperativeKernel((void*)k_tail, dim3(256), dim3(256), targs, 0, stream);
}

// Round 12
// 180.052 us; speedup vs baseline: 1.9770x; 1.5462x over previous
//
#include <hip/hip_runtime.h>

// Problem constants
#define B_ 32
#define N_ 4096
#define C_ 768
#define H_ 8
#define DH_ 96
#define TILE 8
#define ROWS 256
#define NT (ROWS / TILE)     // 32 tiles per chunk
#define NCH (N_ / ROWS)      // 16 chunks per batch row
#define TFL (TILE * C_)      // floats per tile buffer (6144)

struct F3 { float x, y, z; };

#define BARL() do { asm volatile("s_waitcnt lgkmcnt(0)" ::: "memory"); \
                    __builtin_amdgcn_s_barrier(); } while (0)

// ---- prep: q (LDS-only) then wqe_eff (validated R11) ----------------------
__global__ __launch_bounds__(256) void k_prep(const float* __restrict__ queries,
    const float* __restrict__ Wq, const float* __restrict__ Wkv,
    float* __restrict__ wqe) {
  __shared__ float qh[DH_];
  const int bid = blockIdx.x;
  const int h = bid / 3, coff = (bid % 3) * 256;
  const int tid = threadIdx.x, lane = tid & 63, wv = tid >> 6;

  float4 q0 = *(const float4*)(queries + lane * 4);
  float4 q1 = *(const float4*)(queries + 256 + lane * 4);
  float4 q2 = *(const float4*)(queries + 512 + lane * 4);
#pragma unroll 4
  for (int j = 0; j < 24; ++j) {
    int d = wv * 24 + j;
    const float* wr = Wq + (size_t)(h * DH_ + d) * C_ + lane * 4;
    float4 w0 = *(const float4*)(wr);
    float4 w1 = *(const float4*)(wr + 256);
    float4 w2 = *(const float4*)(wr + 512);
    float a = w0.x * q0.x;
    a = fmaf(w0.y, q0.y, a); a = fmaf(w0.z, q0.z, a); a = fmaf(w0.w, q0.w, a);
    a = fmaf(w1.x, q1.x, a); a = fmaf(w1.y, q1.y, a);
    a = fmaf(w1.z, q1.z, a); a = fmaf(w1.w, q1.w, a);
    a = fmaf(w2.x, q2.x, a); a = fmaf(w2.y, q2.y, a);
    a = fmaf(w2.z, q2.z, a); a = fmaf(w2.w, q2.w, a);
#pragma unroll
    for (int off = 32; off; off >>= 1) a += __shfl_xor(a, off);
    if (lane == 0) qh[d] = a;
  }
  __syncthreads();

  const int c = coff + tid;
  const float* base = Wkv + (size_t)h * DH_ * C_ + c;
  float a = 0.f;
#pragma unroll 8
  for (int d = 0; d < DH_; ++d)
    a = fmaf(qh[d], base[(size_t)d * C_], a);
  wqe[(size_t)h * C_ + c] = a;
}

// ---- single-pass fused (IDENTICAL to R9/R10/R11; measured 111 us) ---------
__global__ __attribute__((amdgpu_flat_work_group_size(256, 256),
                          amdgpu_waves_per_eu(2, 2))) void k_fused(
    const float* __restrict__ x, const float* __restrict__ wqe,
    float* __restrict__ part, float* __restrict__ sout) {
  extern __shared__ __align__(16) float xdyn[];       // 3 * TFL floats
  __shared__ __align__(16) float wlds[TILE][H_];
  __shared__ float sden[4][4];

  const int ch = blockIdx.x, b = blockIdx.y;
  const int tid = threadIdx.x, lane = tid & 63, wid = tid >> 6;
  const int rbase = (wid & 1) * 4;
  const int hbase = (wid >> 1) * 4;
  const int col = lane * 4;
  const float* xc = x + ((size_t)b * N_ + (size_t)ch * ROWS) * C_;

  float4 wqv[4][3];
#pragma unroll
  for (int h = 0; h < 4; ++h)
#pragma unroll
    for (int p = 0; p < 3; ++p)
      wqv[h][p] = *(const float4*)(wqe + (size_t)(hbase + h) * C_ + p * 256 + col);

  float acc[H_][3];
#pragma unroll
  for (int h = 0; h < H_; ++h) { acc[h][0] = 0.f; acc[h][1] = 0.f; acc[h][2] = 0.f; }
  float sreg = 0.f;

#define STAGE(BI, T) do {                                                      \
    const float* gt_ = xc + (size_t)(T) * TFL;                                 \
    float* bn_ = xdyn + (size_t)(BI) * TFL;                                    \
    _Pragma("unroll")                                                          \
    for (int j = 0; j < 6; ++j) {                                              \
      int k = wid * 6 + j;                                                     \
      __builtin_amdgcn_global_load_lds(                                        \
        (const __attribute__((address_space(1))) void*)(gt_ + k * 256 + lane * 4), \
        (__attribute__((address_space(3))) void*)(bn_ + k * 256),              \
        16, 0, 0);                                                             \
    }                                                                          \
  } while (0)

  STAGE(0, 0);
  STAGE(1, 1);

  int bi = 0;
  for (int t = 0; t < NT; ++t) {
    if (t < NT - 1) { asm volatile("s_waitcnt vmcnt(6)" ::: "memory"); }
    else           { asm volatile("s_waitcnt vmcnt(0)" ::: "memory"); }
    BARL();
    if (t + 2 < NT) { int nb = bi + 2; if (nb >= 3) nb -= 3; STAGE(nb, t + 2); }
    const float* xb = xdyn + (size_t)bi * TFL;

#pragma unroll
    for (int rr = 0; rr < 4; ++rr) {
      const int r = rbase + rr;
      const float* xr = xb + r * C_ + col;
      float4 xv0 = *(const float4*)(xr);
      float4 xv1 = *(const float4*)(xr + 256);
      float4 xv2 = *(const float4*)(xr + 512);
      float d[4];
#pragma unroll
      for (int h = 0; h < 4; ++h) {
        float a = xv0.x * wqv[h][0].x;
        a = fmaf(xv0.y, wqv[h][0].y, a);
        a = fmaf(xv0.z, wqv[h][0].z, a);
        a = fmaf(xv0.w, wqv[h][0].w, a);
        a = fmaf(xv1.x, wqv[h][1].x, a);
        a = fmaf(xv1.y, wqv[h][1].y, a);
        a = fmaf(xv1.z, wqv[h][1].z, a);
        a = fmaf(xv1.w, wqv[h][1].w, a);
        a = fmaf(xv2.x, wqv[h][2].x, a);
        a = fmaf(xv2.y, wqv[h][2].y, a);
        a = fmaf(xv2.z, wqv[h][2].z, a);
        a = fmaf(xv2.w, wqv[h][2].w, a);
        d[h] = a;
      }
      const int s1 = lane & 1, s2 = lane & 2;
      float A0 = (s1 ? d[1] : d[0]) + __shfl_xor(s1 ? d[0] : d[1], 1);
      float A1 = (s1 ? d[3] : d[2]) + __shfl_xor(s1 ? d[2] : d[3], 1);
      float Q  = (s2 ? A1 : A0) + __shfl_xor(s2 ? A0 : A1, 2);
      Q += __shfl_xor(Q, 4);
      Q += __shfl_xor(Q, 8);
      Q += __shfl_xor(Q, 16);
      Q += __shfl_xor(Q, 32);
      float w = __expf(Q - 20.f);
      if (lane < 4) { wlds[r][hbase + lane] = w; sreg += w; }
    }
    BARL();

    {
      const int c0 = tid * 3;
#pragma unroll
      for (int r = 0; r < TILE; ++r) {
        float4 wA = *(const float4*)(&wlds[r][0]);
        float4 wB = *(const float4*)(&wlds[r][4]);
        F3 xv = *(const F3*)(xb + r * C_ + c0);
        acc[0][0] = fmaf(wA.x, xv.x, acc[0][0]);
        acc[0][1] = fmaf(wA.x, xv.y, acc[0][1]);
        acc[0][2] = fmaf(wA.x, xv.z, acc[0][2]);
        acc[1][0] = fmaf(wA.y, xv.x, acc[1][0]);
        acc[1][1] = fmaf(wA.y, xv.y, acc[1][1]);
        acc[1][2] = fmaf(wA.y, xv.z, acc[1][2]);
        acc[2][0] = fmaf(wA.z, xv.x, acc[2][0]);
        acc[2][1] = fmaf(wA.z, xv.y, acc[2][1]);
        acc[2][2] = fmaf(wA.z, xv.z, acc[2][2]);
        acc[3][0] = fmaf(wA.w, xv.x, acc[3][0]);
        acc[3][1] = fmaf(wA.w, xv.y, acc[3][1]);
        acc[3][2] = fmaf(wA.w, xv.z, acc[3][2]);
        acc[4][0] = fmaf(wB.x, xv.x, acc[4][0]);
        acc[4][1] = fmaf(wB.x, xv.y, acc[4][1]);
        acc[4][2] = fmaf(wB.x, xv.z, acc[4][2]);
        acc[5][0] = fmaf(wB.y, xv.x, acc[5][0]);
        acc[5][1] = fmaf(wB.y, xv.y, acc[5][1]);
        acc[5][2] = fmaf(wB.y, xv.z, acc[5][2]);
        acc[6][0] = fmaf(wB.z, xv.x, acc[6][0]);
        acc[6][1] = fmaf(wB.z, xv.y, acc[6][1]);
        acc[6][2] = fmaf(wB.z, xv.z, acc[6][2]);
        acc[7][0] = fmaf(wB.w, xv.x, acc[7][0]);
        acc[7][1] = fmaf(wB.w, xv.y, acc[7][1]);
        acc[7][2] = fmaf(wB.w, xv.z, acc[7][2]);
      }
    }
    ++bi; if (bi >= 3) bi -= 3;
  }

  {
    const int c0 = tid * 3;
    float* pp = part + ((size_t)(b * NCH + ch) * H_) * C_ + c0;
#pragma unroll
    for (int h = 0; h < H_; ++h) {
      F3 o = { acc[h][0], acc[h][1], acc[h][2] };
      *(F3*)(pp + (size_t)h * C_) = o;
    }
    if (lane < 4) sden[wid][lane] = sreg;
    BARL();
    if (tid < H_) {
      int hh = tid >> 2;
      float den = sden[2 * hh][tid & 3] + sden[2 * hh + 1][tid & 3];
      sout[(size_t)(b * NCH + ch) * H_ + tid] = den;
    }
  }
#undef STAGE
}

// ---- combout: block (h,b) combines chunk partials (xbar in LDS only) and
// computes out1[b, h*96 .. h*96+95] ------------------------------------------
__global__ __launch_bounds__(256) void k_combout(
    const float* __restrict__ part, const float* __restrict__ spart,
    const float* __restrict__ Wkv, float* __restrict__ out1) {
  __shared__ __align__(16) float xb[C_];
  const int h = blockIdx.x, b = blockIdx.y;
  const int tid = threadIdx.x, lane = tid & 63, wv = tid >> 6;

  // denominator (all threads redundantly; broadcast loads)
  const float* sp = spart + (size_t)b * NCH * H_ + h;
  float den = 0.f;
#pragma unroll
  for (int ch = 0; ch < NCH; ++ch) den += sp[(size_t)ch * H_];
  const float inv = 1.f / den;

  // xbar[c0..c0+2] = inv * sum_ch part
  const int c0 = tid * 3;
  const float* pp = part + ((size_t)(b * NCH) * H_ + h) * C_ + c0;
  float a0 = 0.f, a1 = 0.f, a2 = 0.f;
#pragma unroll
  for (int ch = 0; ch < NCH; ++ch) {
    const float* p = pp + (size_t)ch * H_ * C_;
    a0 += p[0]; a1 += p[1]; a2 += p[2];
  }
  xb[c0] = a0 * inv; xb[c0 + 1] = a1 * inv; xb[c0 + 2] = a2 * inv;
  __syncthreads();

  // out1: 96 dots vs Wkv value rows
  float4 x0 = *(const float4*)(&xb[lane * 4]);
  float4 x1 = *(const float4*)(&xb[256 + lane * 4]);
  float4 x2 = *(const float4*)(&xb[512 + lane * 4]);
#pragma unroll 4
  for (int j = 0; j < 24; ++j) {
    int e = h * DH_ + wv * 24 + j;
    const float* wr = Wkv + (size_t)(C_ + e) * C_ + lane * 4;
    float4 w0 = *(const float4*)(wr);
    float4 w1 = *(const float4*)(wr + 256);
    float4 w2 = *(const float4*)(wr + 512);
    float a = w0.x * x0.x;
    a = fmaf(w0.y, x0.y, a); a = fmaf(w0.z, x0.z, a); a = fmaf(w0.w, x0.w, a);
    a = fmaf(w1.x, x1.x, a); a = fmaf(w1.y, x1.y, a);
    a = fmaf(w1.z, x1.z, a); a = fmaf(w1.w, x1.w, a);
    a = fmaf(w2.x, x2.x, a); a = fmaf(w2.y, x2.y, a);
    a = fmaf(w2.z, x2.z, a); a = fmaf(w2.w, x2.w, a);
#pragma unroll
    for (int off = 32; off; off >>= 1) a += __shfl_xor(a, off);
    if (lane == 0) out1[(size_t)b * C_ + e] = a;
  }
}

// ---- proj: block (esl,b): y[b, esl*96..+95] = out1[b] @ Wproj^T + b --------
__global__ __launch_bounds__(256) void k_proj2(
    const float* __restrict__ out1, const float* __restrict__ Wproj,
    const float* __restrict__ bproj, float* __restrict__ y) {
  __shared__ __align__(16) float xb[C_];
  const int esl = blockIdx.x, b = blockIdx.y;
  const int tid = threadIdx.x, lane = tid & 63, wv = tid >> 6;

  if (tid < 192) ((float4*)xb)[tid] = ((const float4*)(out1 + (size_t)b * C_))[tid];
  __syncthreads();

  float4 x0 = *(const float4*)(&xb[lane * 4]);
  float4 x1 = *(const float4*)(&xb[256 + lane * 4]);
  float4 x2 = *(const float4*)(&xb[512 + lane * 4]);
#pragma unroll 4
  for (int j = 0; j < 24; ++j) {
    int e = esl * DH_ + wv * 24 + j;
    const float* wr = Wproj + (size_t)e * C_ + lane * 4;
    float4 w0 = *(const float4*)(wr);
    float4 w1 = *(const float4*)(wr + 256);
    float4 w2 = *(const float4*)(wr + 512);
    float a = w0.x * x0.x;
    a = fmaf(w0.y, x0.y, a); a = fmaf(w0.z, x0.z, a); a = fmaf(w0.w, x0.w, a);
    a = fmaf(w1.x, x1.x, a); a = fmaf(w1.y, x1.y, a);
    a = fmaf(w1.z, x1.z, a); a = fmaf(w1.w, x1.w, a);
    a = fmaf(w2.x, x2.x, a); a = fmaf(w2.y, x2.y, a);
    a = fmaf(w2.z, x2.z, a); a = fmaf(w2.w, x2.w, a);
#pragma unroll
    for (int off = 32; off; off >>= 1) a += __shfl_xor(a, off);
    if (lane == 0) y[(size_t)b * C_ + e] = a + bproj[e];
  }
}

extern "C" void kernel_launch(void* const* d_in, const int* in_sizes, int n_in,
                              void* d_out, int out_size, void* d_ws, size_t ws_size,
                              hipStream_t stream) {
  const float* x       = (const float*)d_in[0];
  const float* queries = (const float*)d_in[1];
  const float* Wq      = (const float*)d_in[2];
  const float* Wkv     = (const float*)d_in[3];
  const float* Wproj   = (const float*)d_in[4];
  const float* bproj   = (const float*)d_in[5];
  float* y  = (float*)d_out;
  float* ws = (float*)d_ws;

  float* wqe   = ws + 1024;                            // 6144
  float* spart = ws + 8192;                            // B*NCH*H = 4096
  float* part  = ws + 16384;                           // B*NCH*H*C = 3145728
  float* out1  = part + (size_t)B_ * NCH * H_ * C_;    // 24576

  hipLaunchKernelGGL(k_prep,    dim3(24),       dim3(256), 0, stream, queries, Wq, Wkv, wqe);
  hipLaunchKernelGGL(k_fused,   dim3(NCH, B_),  dim3(256),
                     3 * TFL * sizeof(float), stream, x, wqe, part, spart);
  hipLaunchKernelGGL(k_combout, dim3(H_, B_),   dim3(256), 0, stream, part, spart, Wkv, out1);
  hipLaunchKernelGGL(k_proj2,   dim3(H_, B_),   dim3(256), 0, stream, out1, Wproj, bproj, y);
}